// Round 1
// baseline (277.454 us; speedup 1.0000x reference)
//
#include <hip/hip_runtime.h>

// Problem constants (fixed in the reference file)
#define OHh   60
#define OWw   60
#define NBINS (OHh * OWw)   // 3600
#define NB    64            // batches
#define NS    4096          // spikes per batch
#define CAP   128

#define NW     4            // waves per block
#define SEG    (NS / NW)    // 1024 spikes scanned per wave
#define CH     (SEG / 64)   // 16 chunks per wave
#define WSLOTS 32           // real slots per (wave,bin); row WSLOTS = dummy sink
                            // (per-bin-per-wave ~ Poisson(7.1); P(>32) ~ 1e-12)
#define PRE0   64           // slots [PRE0, CAP) prefilled -1 during scan
#define HCAP   176          // collected-hit cap per wave segment (lambda ~80, ~10.7 sigma)
#define HSINK  192          // per-lane sink region base in hits[] (idx = 192+lane)

// One 4-wave block per (batch, output row); lane == ow (lanes 60..63 parked).
// R9: the R7/R8 scan broadcast-tested every halo hit across 60 lanes (~5
// winners, ~92% wasted lane work; ~160 LDS instrs/wave, LDS-pipe/SALU bound
// per R7 PMC). R9 batches 12 hits x 5 kw-lanes: each lane computes its ONE
// (bin, ckk) candidate; stable per-bin rank (s-order!) via 6-ballot
// match-any on the bin route + mbcnt (lane order == hit order == s order).
// Counts live in LDS cnt[wv][bin]; stage flips to [bin][slot] (dump read
// stride 33 shorts = 16.5 dwords -> exact 2-way bank alias, free).
// Hits are collected for the whole segment first (16 chunk ballots into
// hits[]), then consumed in ~7 full batches. Prefill of slots [64,128)
// stays hidden under the scan (proven R8 pattern, WRITE_SIZE ~= 1.0x).
__global__ __launch_bounds__(256) void sort_spikes_row4(
    const int* __restrict__ spikes, int* __restrict__ out) {
    const int bid  = (int)blockIdx.x;
    const int b    = bid & (NB - 1);   // batch-minor -> batch b pinned to XCD b%8
    const int row  = bid >> 6;         // output row oh, 0..59
    const int tid  = (int)threadIdx.x;
    const int wv   = tid >> 6;
    const int lane = tid & 63;
    const bool valid = lane < OWw;

    __shared__ short stage[NW][64][WSLOTS + 1];            // [wave][bin][slot] 16896 B
    __shared__ __align__(8) unsigned short hits[NW][256];  // 2048 B; sinks at [192+lane]
    __shared__ int   cnt[NW][64];                          // 1024 B
    __shared__ int   ovf;                                  // total ~19.9 KB -> 8 blk/CU (LDS)

    if (tid == 0) ovf = 0;   // benign: waves can only set ovf ~1000 instrs later
    cnt[wv][lane] = 0;

    const int* __restrict__ sp   = spikes + b * NS + wv * SEG;
    int* __restrict__       outb = out + (size_t)b * (CAP * NBINS) + row * OWw;

    // Issue all 16 chunk loads up front (deep vmcnt pipeline; L2-resident
    // after the first of a batch's 60 blocks touches them).
    int vs[CH];
#pragma unroll
    for (int c = 0; c < CH; ++c) vs[c] = sp[c * 64 + lane];

    unsigned short* const hitbuf = &hits[wv][0];
    const int sinkw = HSINK + lane;   // per-lane LDS sink (no same-address pileup)

    // ---- Phase 1: collect halo hits for the whole segment, s-ordered. ----
    // Payload pack: (w<<8)|(c<<3)|kh  (6+5+3 = 14 bits) -- no *25 here; the
    // ckk multiply moves to the batch phase where only ~1/8 as many lanes run it.
    int hbase = 0;
#pragma unroll
    for (int c = 0; c < CH; ++c) {
        const int v  = vs[c];
        const int kh = ((v >> 6) & 63) - row;
        const bool halo = (unsigned)kh < 5u;
        const unsigned short P =
            (unsigned short)(((v & 63) << 8) | ((v >> 12) << 3) | (kh & 7));

        const unsigned long long mask = __ballot(halo);   // wave-uniform
        const int pos = __builtin_amdgcn_mbcnt_hi(
            (unsigned)(mask >> 32),
            __builtin_amdgcn_mbcnt_lo((unsigned)mask, 0));  // rank among halo lanes
        const int idx = halo ? (hbase + pos) : sinkw;  // halo idx <= 175+63 = 238 < 256
        hitbuf[idx] = P;                               // s-order preserved
        hbase = min(hbase + (int)__popcll(mask), HCAP);

        // Hidden write: one -1 slot-row per chunk -> slots [64,128) done by
        // scan end (wv*CH+c spans 0..63). Contiguous 240 B run, paced under scan.
        if (valid) outb[(PRE0 + wv * CH + c) * NBINS + lane] = -1;
    }
    if (hbase >= HCAP && lane == 0) ovf = 1;  // truncated hit list (P ~ 1e-21)

    // ---- Phase 2: batched scatter, 12 hits x 5 kw-lanes per iteration. ----
    const int qi  = (lane < 60) ? (lane / 5) : 4096;  // hit sub-index; parked => never valid
    const int kwc = lane - qi * 5;                    // lane % 5 (parked: garbage, routed out)

    const int n = hbase;                 // wave-uniform
    short* const stg = &stage[wv][0][0];
    int*   const cw  = &cnt[wv][0];
    for (int hb = 0; hb < n; hb += 12) {             // uniform trip count
        const int  hidx = hb + qi;
        const bool hv   = hidx < n;
        const int  ridx = hv ? hidx : sinkw;
        const unsigned P = hitbuf[ridx];             // ds_read_u16; 5-lane groups share addr
        const int  w    = (int)(P >> 8);
        const int  bin  = w - kwc;                   // this lane's candidate ow
        const bool ok   = hv & ((unsigned)bin < 60u);
        const int  route = ok ? bin : 62;            // bins 60..63 are sink rows
        const int  val  = ((int)((P >> 3) & 31)) * 25 + ((int)(P & 7)) * 5 + kwc;  // ckk

        // match-any over 6-bit route -> same-bin lane mask m
        unsigned long long m = ~0ull;
#pragma unroll
        for (int t = 0; t < 6; ++t) {
            const bool bit = (route >> t) & 1;
            const unsigned long long bb = __ballot(bit);
            m &= bit ? bb : ~bb;
        }
        // lane order == (hit, kw) lex order == s order (same hit never hits
        // one bin twice) -> rank is the stable s-rank within this batch.
        const int rank = __builtin_amdgcn_mbcnt_hi(
            (unsigned)(m >> 32), __builtin_amdgcn_mbcnt_lo((unsigned)m, 0));
        const int tot  = (int)__popcll(m);
        const int base = cw[route];                  // ds_read gather, ~2-way banks
        const int slot = min(base + rank, WSLOTS);   // clamp into dummy slot 32
        stg[route * (WSLOTS + 1) + slot] = (short)val;
        if (rank == tot - 1) cw[route] = base + tot; // last same-bin lane writes back
    }

    {
        const int mycnt = cw[lane];
        if (__ballot(mycnt > WSLOTS) && lane == 0) ovf = 1;  // lost 33rd entry
    }
    __syncthreads();

    if (ovf == 0) {
        if (valid) {
            const int c0 = cnt[0][lane], c1 = cnt[1][lane];
            const int c2 = cnt[2][lane], c3 = cnt[3][lane];
            const int o1 = c0, o2 = c0 + c1, o3 = o2 + c2;
            const int total = o3 + c3;                 // <= 128
            // Dump slots [0,64): 16 per wave, wave order == s order.
#pragma unroll 4
            for (int i = 0; i < PRE0 / NW; ++i) {
                const int k = wv * (PRE0 / NW) + i;
                int val = -1;
                if (k < total) {
                    int wsel = 0, base = 0;
                    if (k >= o1) { wsel = 1; base = o1; }
                    if (k >= o2) { wsel = 2; base = o2; }
                    if (k >= o3) { wsel = 3; base = o3; }
                    val = (int)stage[wsel][lane][k - base];  // stride 33 shorts: 2-way, free
                }
                outb[k * NBINS + lane] = val;          // contiguous 240 B run
            }
            // Astronomically rare: overwrite prefilled -1s with real values.
            for (int k = PRE0 + wv; k < total && k < CAP; k += NW) {
                int wsel = 0, base = 0;
                if (k >= o1) { wsel = 1; base = o1; }
                if (k >= o2) { wsel = 2; base = o2; }
                if (k >= o3) { wsel = 3; base = o3; }
                outb[k * NBINS + lane] = (int)stage[wsel][lane][k - base];
            }
        }
    } else if (wv == 0) {
        // Fallback: staging overflow (P ~ 1e-6/launch on random input).
        // Serial redo, direct global stores; overwrites any prefilled -1s.
        const int* __restrict__ spf = spikes + b * NS;
        int cc = 0;
        for (int c = 0; c < NS / 64; ++c) {
            const int v = spf[c * 64 + lane];
            const int h = (v >> 6) & 63;
            unsigned long long mask = __ballot((unsigned)(h - row) < 5u);
            while (mask) {
                const int j = (int)__builtin_ctzll(mask);
                mask &= mask - 1;
                const int vj =
                    __builtin_amdgcn_readlane(v, __builtin_amdgcn_readfirstlane(j));
                const int wj  = vj & 63;
                const int khj = ((vj >> 6) & 63) - row;
                const int cj  = vj >> 12;
                const int kw  = wj - lane;
                if (((unsigned)kw < 5u) & valid) {
                    if (cc < CAP)
                        outb[cc * NBINS + lane] = cj * 25 + khj * 5 + kw;
                    ++cc;
                }
            }
        }
        if (valid)
            for (int k = cc; k < CAP; ++k) outb[k * NBINS + lane] = -1;
    }
}

extern "C" void kernel_launch(void* const* d_in, const int* in_sizes, int n_in,
                              void* d_out, int out_size, void* d_ws, size_t ws_size,
                              hipStream_t stream) {
    const int* spikes = (const int*)d_in[0];  // (B, S, 1, 1) int32
    // d_in[1] (indices table) unused: membership is pure arithmetic.
    int* out = (int*)d_out;                   // (B, CAP, OH, OW) int32

    dim3 grid(OHh * NB);                      // 3840 blocks, batch-minor
    dim3 block(256);                          // 4 waves/block
    sort_spikes_row4<<<grid, block, 0, stream>>>(spikes, out);
}

// Round 2
// 153.599 us; speedup vs baseline: 1.8063x; 1.8063x over previous
//
#include <hip/hip_runtime.h>

// Problem constants (fixed in the reference file)
#define OHh   60
#define OWw   60
#define NBINS (OHh * OWw)   // 3600
#define NB    64            // batches
#define NS    4096          // spikes per batch
#define CAP   128

#define NW     4            // waves per block
#define RPB    2            // rows per block (row pair)
#define RG     (OHh / RPB)  // 30 row-groups
#define SEGS   2            // spike-stream halves (waves per row)
#define SEG    (NS / SEGS)  // 2048 spikes scanned per wave
#define CH     (SEG / 64)   // 32 chunks per wave
#define WSLOTS 40           // staged slots per (wave,bin) (+1 dummy row)
                            // per-(wave,bin) ~ Poisson(12.8); P(>40) ~ 3e-10
#define PRE0   64           // slots [PRE0, CAP) prefilled -1 during scan
                            // (per-bin row total ~ Poisson(25.6); P(>64) ~ 1e-11)

// R10: block = (batch, ROW PAIR); lane == ow. R9 post-mortem: the kernel
// floor is the scattered-240B write drain (WRITE_SIZE 1.56x output, ~2.6 TB/s
// in R8), NOT the scan -- which is why R8's overlap was neutral. R10 keeps
// R8's proven broadcast scan verbatim and pairs rows so the two 240 B pieces
// of each (slot k) run are issued concurrently by wave pairs (0,2)/(1,3) and
// merge in L2 into 480 B aligned runs (rg*480 % 64 == 0). Waves 0,1 serve
// row 2rg over spike halves 0,1; waves 2,3 serve row 2rg+1. s-order per row
// = (segment 0 entries, then segment 1 entries), preserved by the dump merge.
__global__ __launch_bounds__(256) void sort_spikes_rowpair(
    const int* __restrict__ spikes, int* __restrict__ out) {
    const int bid  = (int)blockIdx.x;
    const int b    = bid & (NB - 1);   // batch-minor -> batch b pinned to XCD b%8
    const int rg   = bid >> 6;         // row-group 0..29
    const int tid  = (int)threadIdx.x;
    const int wv   = tid >> 6;
    const int lane = tid & 63;
    const bool valid  = lane < OWw;
    const int  lane_c = valid ? lane : 127;  // parked lanes: window test auto-fails

    const int rsub = wv >> 1;          // which of the 2 rows this wave serves
    const int seg  = wv & 1;           // which spike half this wave scans
    const int row  = rg * RPB + rsub;  // output row oh

    __shared__ short          stage[NW][WSLOTS + 1][64];  // 20992 B (+1 dummy sink)
    __shared__ unsigned short hits[NW][64];               // compacted chunk payloads
    __shared__ int            cnt[NW][64];
    __shared__ int            ovf;                        // ~22.5 KB -> 7 blocks/CU

    if (tid == 0) ovf = 0;

    const int* __restrict__ sp   = spikes + b * NS + seg * SEG;
    int* __restrict__       outb = out + (size_t)b * (CAP * NBINS) + row * OWw;

    unsigned short* const hitbuf      = &hits[wv][0];
    short* const          stage_lane  = &stage[wv][0][lane];      // + count*64 shorts
    short* const          stage_dummy = &stage[wv][WSLOTS][lane]; // sink row

    int count = 0;
    // 32 chunks in two register batches of 16 (bounds VGPR pressure).
#pragma unroll
    for (int half = 0; half < 2; ++half) {
        int vs[16];
#pragma unroll
        for (int c = 0; c < 16; ++c) vs[c] = sp[(half * 16 + c) * 64 + lane];

#pragma unroll
        for (int c = 0; c < 16; ++c) {
            const int cc  = half * 16 + c;
            const int v   = vs[c];
            const int kh  = ((v >> 6) & 63) - row;
            const bool halo = (unsigned)kh < 5u;
            const int w   = v & 63;
            const int A   = (v >> 12) * 25 + kh * 5 + w;  // ckk_base + w, fits 10 bits
            const unsigned short P = (unsigned short)((w << 10) | A);

            const unsigned long long mask = __ballot(halo);   // wave-uniform
            const int pos = __builtin_amdgcn_mbcnt_hi(
                (unsigned)(mask >> 32),
                __builtin_amdgcn_mbcnt_lo((unsigned)mask, 0));  // rank among halo lanes
            if (halo) hitbuf[pos] = P;                          // s-order preserved
            const int n = __popcll(mask);                       // uniform

            for (int i = 0; i < n; ++i) {            // uniform trip count
                const int Pj  = (int)hitbuf[i];      // ds_read_u16 same-addr broadcast
                const int kw  = (Pj >> 10) - lane_c; // per-lane window offset
                const bool inwin = (unsigned)kw < 5u;
                const int val = (Pj & 0x3ff) - lane_c;           // == ckk when inwin
                short* a = (inwin & (count < WSLOTS))
                               ? (stage_lane + count * 64)       // count*128 B
                               : stage_dummy;
                *a = (short)val;                      // garbage to sink is fine
                count += inwin;
            }

            // Hidden write: one -1 slot-row per chunk for THIS wave's row.
            // seg*CH+cc spans 0..63 across the row's two waves -> slots [64,128).
            if (valid) outb[(PRE0 + seg * CH + cc) * NBINS + lane] = -1;
        }
    }
    cnt[wv][lane] = count;
    if (__ballot(count > WSLOTS) && lane == 0) ovf = 1;  // benign multi-write
    __syncthreads();

    if (ovf == 0) {
        if (valid) {
            const int w0 = rsub * SEGS;              // row's segment-0 wave index
            const int c0 = cnt[w0][lane], c1 = cnt[w0 + 1][lane];
            const int total = c0 + c1;               // <= 80
            const int kbase = seg * 32;              // this wave dumps k in [kbase,kbase+32)
            // Wave pairs (0,2) and (1,3) iterate the same k for adjacent rows:
            // their 240 B pieces coalesce into 480 B aligned runs in L2.
#pragma unroll 4
            for (int i = 0; i < 32; ++i) {
                const int k = kbase + i;
                int val = -1;
                if (k < total) {
                    const int wsel = (k >= c0) ? (w0 + 1) : w0;
                    const int base = (k >= c0) ? c0 : 0;
                    val = (int)stage[wsel][k - base][lane];  // bank=lane>>1, 2-way free
                }
                outb[k * NBINS + lane] = val;
            }
            // Astronomically rare: row total > 64 -> overwrite prefilled -1s.
            for (int k = PRE0 + seg; k < total && k < CAP; k += SEGS) {
                const int wsel = (k >= c0) ? (w0 + 1) : w0;
                const int base = (k >= c0) ? c0 : 0;
                outb[k * NBINS + lane] = (int)stage[wsel][k - base][lane];
            }
        }
    } else if (seg == 0) {
        // Fallback (P ~ 1e-4/launch): waves 0 and 2 each redo their own row
        // serially over all 4096 spikes, direct global stores.
        const int* __restrict__ spf = spikes + b * NS;
        int cc = 0;
        for (int c = 0; c < NS / 64; ++c) {
            const int v = spf[c * 64 + lane];
            const int h = (v >> 6) & 63;
            unsigned long long mask = __ballot((unsigned)(h - row) < 5u);
            while (mask) {
                const int j = (int)__builtin_ctzll(mask);
                mask &= mask - 1;
                const int vj =
                    __builtin_amdgcn_readlane(v, __builtin_amdgcn_readfirstlane(j));
                const int wj  = vj & 63;
                const int khj = ((vj >> 6) & 63) - row;
                const int cj  = vj >> 12;
                const int kw  = wj - lane;
                if (((unsigned)kw < 5u) & valid) {
                    if (cc < CAP)
                        outb[cc * NBINS + lane] = cj * 25 + khj * 5 + kw;
                    ++cc;
                }
            }
        }
        if (valid)
            for (int k = cc; k < CAP; ++k) outb[k * NBINS + lane] = -1;
    }
}

extern "C" void kernel_launch(void* const* d_in, const int* in_sizes, int n_in,
                              void* d_out, int out_size, void* d_ws, size_t ws_size,
                              hipStream_t stream) {
    const int* spikes = (const int*)d_in[0];  // (B, S, 1, 1) int32
    // d_in[1] (indices table) unused: membership is pure arithmetic.
    int* out = (int*)d_out;                   // (B, CAP, OH, OW) int32

    dim3 grid(RG * NB);                       // 1920 blocks, batch-minor
    dim3 block(256);                          // 4 waves/block
    sort_spikes_rowpair<<<grid, block, 0, stream>>>(spikes, out);
}

// Round 3
// 153.549 us; speedup vs baseline: 1.8069x; 1.0003x over previous
//
#include <hip/hip_runtime.h>

// Problem constants (fixed in the reference file)
#define OHh   60
#define OWw   60
#define NBINS (OHh * OWw)   // 3600
#define NB    64            // batches
#define NS    4096          // spikes per batch
#define CAP   128

#define NW     16           // waves per block (1024 threads)
#define RPB    4            // rows per block; 4*240 B = 960 B = 15 full sectors
#define RG     (OHh / RPB)  // 15 row-groups
#define SEGS   4            // spike-stream quarters (waves per row)
#define SEG    (NS / SEGS)  // 1024 spikes scanned per wave (== R8 granularity)
#define CH     (SEG / 64)   // 16 chunks per wave
#define WSLOTS 32           // staged slots per (wave,bin) (+1 dummy row)
                            // per-(wave,bin) ~ Poisson(6.25); P(>32) ~ 5e-13
#define PRE0   64           // slots [PRE0, CAP) prefilled -1 during scan
                            // (per-bin row total ~ Poisson(25); P(>64) ~ 1e-11)

// R11: block = (batch, FOUR consecutive rows), 16 waves. R10 post-mortem:
// 2-row runs (480 B) are misaligned by 32 B for odd pairs and relied on
// temporal L2 merge; and doubling per-wave serial scan cost ~5 us. R11 makes
// alignment structural: 4 rows x 240 B = 960 B runs at 960*rg offsets,
// 64 B-aligned at BOTH ends -> zero partial/shared sectors cross-block;
// interior piece boundaries are intra-block and merge in L2. Per-wave scan
// granularity reverts to R8's proven 1024 spikes / 16 chunks / ~80 hits.
// Wave wv: rsub = wv>>2 (row within group), seg = wv&3 (spike quarter).
// s-order per row = seg0|seg1|seg2|seg3, merged via 4-count prefix in dump.
// LDS 73.7 KB -> 2 blocks/CU -> 32 waves/CU.
__global__ __launch_bounds__(1024) void sort_spikes_row4x(
    const int* __restrict__ spikes, int* __restrict__ out) {
    const int bid  = (int)blockIdx.x;
    const int b    = bid & (NB - 1);   // batch-minor -> batch b pinned to XCD b%8
    const int rg   = bid >> 6;         // row-group 0..14
    const int tid  = (int)threadIdx.x;
    const int wv   = tid >> 6;
    const int lane = tid & 63;
    const bool valid  = lane < OWw;
    const int  lane_c = valid ? lane : 127;  // parked lanes: window test auto-fails

    const int rsub = wv >> 2;          // which of the 4 rows this wave serves
    const int seg  = wv & 3;           // which spike quarter this wave scans
    const int row  = rg * RPB + rsub;  // output row oh

    __shared__ short          stage[NW][WSLOTS + 1][64];  // 67584 B (+1 dummy sink)
    __shared__ unsigned short hits[NW][64];               // 2048 B
    __shared__ int            cnt[NW][64];                // 4096 B
    __shared__ int            ovf;                        // total 73.7 KB -> 2 blk/CU

    if (tid == 0) ovf = 0;   // benign: waves can only set ovf ~1000 instrs later

    const int* __restrict__ sp   = spikes + b * NS + seg * SEG;
    int* __restrict__       outb = out + (size_t)b * (CAP * NBINS) + row * OWw;

    // Issue all 16 chunk loads up front (deep vmcnt pipeline; L2-resident
    // after the first of a batch's 15 blocks touches them).
    int vs[CH];
#pragma unroll
    for (int c = 0; c < CH; ++c) vs[c] = sp[c * 64 + lane];

    unsigned short* const hitbuf      = &hits[wv][0];
    short* const          stage_lane  = &stage[wv][0][lane];      // + count*64 shorts
    short* const          stage_dummy = &stage[wv][WSLOTS][lane]; // sink row

    int count = 0;
#pragma unroll
    for (int c = 0; c < CH; ++c) {
        const int v   = vs[c];
        const int kh  = ((v >> 6) & 63) - row;
        const bool halo = (unsigned)kh < 5u;
        const int w   = v & 63;
        const int A   = (v >> 12) * 25 + kh * 5 + w;  // ckk_base + w, fits 10 bits
        const unsigned short P = (unsigned short)((w << 10) | A);

        const unsigned long long mask = __ballot(halo);   // wave-uniform
        const int pos = __builtin_amdgcn_mbcnt_hi(
            (unsigned)(mask >> 32),
            __builtin_amdgcn_mbcnt_lo((unsigned)mask, 0));  // rank among halo lanes
        if (halo) hitbuf[pos] = P;                          // s-order preserved
        const int n = __popcll(mask);                       // uniform

        for (int i = 0; i < n; ++i) {            // uniform trip count
            const int Pj  = (int)hitbuf[i];      // ds_read_u16 same-addr broadcast
            const int kw  = (Pj >> 10) - lane_c; // per-lane window offset
            const bool inwin = (unsigned)kw < 5u;
            const int val = (Pj & 0x3ff) - lane_c;           // == ckk when inwin
            short* a = (inwin & (count < WSLOTS))
                           ? (stage_lane + count * 64)       // count*128 B
                           : stage_dummy;
            *a = (short)val;                      // garbage to sink is fine
            count += inwin;
        }

        // Hidden write: one -1 slot-row per chunk for THIS wave's row.
        // seg*CH+c spans 0..63 across the row's four waves -> slots [64,128).
        // The 4 rsub-waves' 240 B pieces form a 960 B aligned run per slot.
        if (valid) outb[(PRE0 + seg * CH + c) * NBINS + lane] = -1;
    }
    cnt[wv][lane] = count;
    if (__ballot(count > WSLOTS) && lane == 0) ovf = 1;  // benign multi-write
    __syncthreads();

    if (ovf == 0) {
        if (valid) {
            const int w0 = rsub * SEGS;              // row's segment-0 wave index
            const int c0 = cnt[w0][lane], c1 = cnt[w0 + 1][lane];
            const int c2 = cnt[w0 + 2][lane], c3 = cnt[w0 + 3][lane];
            const int o1 = c0, o2 = c0 + c1, o3 = o2 + c2;
            const int total = o3 + c3;               // <= 128
            // Dump slots [0,64): 16 per seg-wave; the 4 rsub-waves with the
            // same seg iterate the same k -> 960 B aligned run per iteration.
#pragma unroll 4
            for (int i = 0; i < PRE0 / SEGS; ++i) {
                const int k = seg * (PRE0 / SEGS) + i;
                int val = -1;
                if (k < total) {
                    int wsel = w0, base = 0;
                    if (k >= o1) { wsel = w0 + 1; base = o1; }
                    if (k >= o2) { wsel = w0 + 2; base = o2; }
                    if (k >= o3) { wsel = w0 + 3; base = o3; }
                    val = (int)stage[wsel][k - base][lane];  // bank=lane>>1, 2-way free
                }
                outb[k * NBINS + lane] = val;
            }
            // Astronomically rare: row total > 64 -> overwrite prefilled -1s.
            for (int k = PRE0 + seg; k < total && k < CAP; k += SEGS) {
                int wsel = w0, base = 0;
                if (k >= o1) { wsel = w0 + 1; base = o1; }
                if (k >= o2) { wsel = w0 + 2; base = o2; }
                if (k >= o3) { wsel = w0 + 3; base = o3; }
                outb[k * NBINS + lane] = (int)stage[wsel][k - base][lane];
            }
        }
    } else if (seg == 0) {
        // Fallback (P ~ 1e-6/launch): the 4 seg-0 waves each redo their own
        // row serially over all 4096 spikes, direct global stores.
        const int* __restrict__ spf = spikes + b * NS;
        int cc = 0;
        for (int c = 0; c < NS / 64; ++c) {
            const int v = spf[c * 64 + lane];
            const int h = (v >> 6) & 63;
            unsigned long long mask = __ballot((unsigned)(h - row) < 5u);
            while (mask) {
                const int j = (int)__builtin_ctzll(mask);
                mask &= mask - 1;
                const int vj =
                    __builtin_amdgcn_readlane(v, __builtin_amdgcn_readfirstlane(j));
                const int wj  = vj & 63;
                const int khj = ((vj >> 6) & 63) - row;
                const int cj  = vj >> 12;
                const int kw  = wj - lane;
                if (((unsigned)kw < 5u) & valid) {
                    if (cc < CAP)
                        outb[cc * NBINS + lane] = cj * 25 + khj * 5 + kw;
                    ++cc;
                }
            }
        }
        if (valid)
            for (int k = cc; k < CAP; ++k) outb[k * NBINS + lane] = -1;
    }
}

extern "C" void kernel_launch(void* const* d_in, const int* in_sizes, int n_in,
                              void* d_out, int out_size, void* d_ws, size_t ws_size,
                              hipStream_t stream) {
    const int* spikes = (const int*)d_in[0];  // (B, S, 1, 1) int32
    // d_in[1] (indices table) unused: membership is pure arithmetic.
    int* out = (int*)d_out;                   // (B, CAP, OH, OW) int32

    dim3 grid(RG * NB);                       // 960 blocks, batch-minor
    dim3 block(NW * 64);                      // 16 waves/block
    sort_spikes_row4x<<<grid, block, 0, stream>>>(spikes, out);
}